// Round 8
// baseline (152.529 us; speedup 1.0000x reference)
//
#include <hip/hip_runtime.h>

#define N_NODES 100000
#define D 128
#define E_POS 262144
#define E_NEG 262144
#define E_TOT (E_POS + E_NEG)
#define NT 1563           // ceil(N_NODES/64) node tiles

typedef __attribute__((ext_vector_type(8))) short short8;  // 8 bf16 (4 VGPRs)
typedef __attribute__((ext_vector_type(4))) float f4;      // MFMA C/D frag

__device__ __forceinline__ unsigned f2bf_u(float f) {
    // round-to-nearest-even fp32 -> bf16 (inputs finite; no NaN path)
    unsigned u = __float_as_uint(f);
    return (u + 0x7fffu + ((u >> 16) & 1u)) >> 16;
}

__device__ __forceinline__ void glds16(const void* g, void* l) {
    // async 16-B global->LDS; LDS dest = l + lane*16 (wave-uniform l)
    __builtin_amdgcn_global_load_lds(
        (const __attribute__((address_space(1))) void*)g,
        (__attribute__((address_space(3))) void*)l, 16, 0, 0);
}

// ---------------------------------------------------------------------------
// Prep: pack W1 (fp32 [256,128]) into bf16 MFMA fragment layout:
//   Wf[((h*4+ks)*4+q)*128 + c][j] = bf16( W1[h*128 + ks*32 + q*8 + j][c] )
// Serves as the A-operand (W1^T) in the swapped-orientation MFMA.
// 64 KB total (L2-resident).
// ---------------------------------------------------------------------------
__global__ __launch_bounds__(256) void pack_w1(
    const float* __restrict__ W1, unsigned short* __restrict__ Wf)
{
    const int tid = blockIdx.x * 256 + threadIdx.x;   // 4096 groups
    if (tid >= 4096) return;
    const int h  = tid >> 11;
    const int ks = (tid >> 9) & 3;
    const int q  = (tid >> 7) & 3;
    const int c  = tid & 127;
    const int kb = h * 128 + ks * 32 + q * 8;
    const float* src = W1 + (size_t)kb * D + c;
    unsigned short tmp[8];
#pragma unroll
    for (int j = 0; j < 8; ++j) tmp[j] = (unsigned short)f2bf_u(src[(size_t)j * D]);
    *(uint4*)(Wf + (size_t)tid * 8) = *(const uint4*)tmp;
}

// ---------------------------------------------------------------------------
// Phase 1 (bf16 MFMA, swapped orientation, persistent + pipelined) —
// unchanged from round 7 (improved; no longer in top-5).
// ---------------------------------------------------------------------------
#define XRS 136   // staging row stride in shorts (272 B: 16-B aligned)
#define ERS 264   // epilogue row stride in shorts (528 B: 16-B aligned)
#define GRID1 783 // gemm grid: 2 tiles/block max

__global__ __launch_bounds__(512, 4) void node_gemm_mfma(
    const float* __restrict__ x,            // [N, 128]
    const unsigned short* __restrict__ Wf,  // packed W1^T frags
    const float* __restrict__ b1,           // [128]
    unsigned short* __restrict__ UVb)       // [N, 256] bf16
{
    __shared__ unsigned short Ls[64 * XRS + 64 * ERS];  // 51200 B
    unsigned short* const Es = Ls + 64 * XRS;           // epilogue region

    const int t    = threadIdx.x;
    const int w    = t >> 6;                // wave 0..7
    const int lane = t & 63;
    const int m16  = lane & 15;
    const int q    = lane >> 4;             // quad 0..3
    const int h    = w >> 2;                // 0=U, 1=V
    const int cbase = (w & 3) * 32;         // col slice within half

    short8 wfr[4][2];
#pragma unroll
    for (int ks = 0; ks < 4; ++ks) {
        const unsigned short* wfb =
            Wf + ((size_t)(((h * 4 + ks) * 4 + q) * 128 + cbase + m16)) * 8;
        wfr[ks][0] = *(const short8*)wfb;
        wfr[ks][1] = *(const short8*)(wfb + 16 * 8);
    }
    float4 badd[2];
#pragma unroll
    for (int ct = 0; ct < 2; ++ct)
        badd[ct] = (h == 0) ? *(const float4*)(b1 + cbase + ct * 16 + q * 4)
                            : make_float4(0.f, 0.f, 0.f, 0.f);

    int tile = blockIdx.x;
    float4 xr[4];
#pragma unroll
    for (int i = 0; i < 4; ++i) {
        const int s  = t + i * 512;
        int gr = tile * 64 + (s >> 5);
        if (gr >= N_NODES) gr = N_NODES - 1;
        xr[i] = *(const float4*)(x + (size_t)gr * D + (s & 31) * 4);
    }

    for (; tile < NT; tile += GRID1) {
        const int nb = tile * 64;

#pragma unroll
        for (int i = 0; i < 4; ++i) {
            const int s = t + i * 512;
            const unsigned p0 = (f2bf_u(xr[i].y) << 16) | f2bf_u(xr[i].x);
            const unsigned p1 = (f2bf_u(xr[i].w) << 16) | f2bf_u(xr[i].z);
            *(uint2*)&Ls[(s >> 5) * XRS + (s & 31) * 4] = make_uint2(p0, p1);
        }
        __syncthreads();   // bar1: stage visible; also guards prev epi reads

        const int ntile = tile + GRID1;
        float4 xr2[4];
        if (ntile < NT) {
#pragma unroll
            for (int i = 0; i < 4; ++i) {
                const int s  = t + i * 512;
                int gr = ntile * 64 + (s >> 5);
                if (gr >= N_NODES) gr = N_NODES - 1;
                xr2[i] = *(const float4*)(x + (size_t)gr * D + (s & 31) * 4);
            }
        } else {
#pragma unroll
            for (int i = 0; i < 4; ++i) xr2[i] = xr[i];
        }

        f4 acc[4][2];
#pragma unroll
        for (int i = 0; i < 4; ++i)
#pragma unroll
            for (int j = 0; j < 2; ++j) acc[i][j] = (f4){0.f, 0.f, 0.f, 0.f};

#pragma unroll
        for (int ks = 0; ks < 4; ++ks) {
            const int kcol = ks * 32 + q * 8;
            short8 xf[4];
#pragma unroll
            for (int rt = 0; rt < 4; ++rt)
                xf[rt] = *(const short8*)&Ls[(rt * 16 + m16) * XRS + kcol];
#pragma unroll
            for (int rt = 0; rt < 4; ++rt)
#pragma unroll
                for (int ct = 0; ct < 2; ++ct)
                    acc[rt][ct] = __builtin_amdgcn_mfma_f32_16x16x32_bf16(
                        wfr[ks][ct], xf[rt], acc[rt][ct], 0, 0, 0);
        }

#pragma unroll
        for (int rt = 0; rt < 4; ++rt)
#pragma unroll
            for (int ct = 0; ct < 2; ++ct) {
                const int node = rt * 16 + m16;
                const int j    = h * 128 + cbase + ct * 16 + q * 4;
                const unsigned p0 =
                    (f2bf_u(acc[rt][ct][1] + badd[ct].y) << 16) |
                     f2bf_u(acc[rt][ct][0] + badd[ct].x);
                const unsigned p1 =
                    (f2bf_u(acc[rt][ct][3] + badd[ct].w) << 16) |
                     f2bf_u(acc[rt][ct][2] + badd[ct].z);
                *(uint2*)&Es[node * ERS + j] = make_uint2(p0, p1);
            }
        __syncthreads();   // bar2: epi visible; stage reads done

        const int r    = t >> 3;
        const int c0   = (t & 7) * 32;
        const int grow = nb + r;
        if (grow < N_NODES) {
            const uint4* s = (const uint4*)&Es[r * ERS + c0];
            uint4* d = (uint4*)(UVb + (size_t)grow * 256 + c0);
#pragma unroll
            for (int i = 0; i < 4; ++i) d[i] = s[i];
        }

#pragma unroll
        for (int i = 0; i < 4; ++i) xr[i] = xr2[i];
    }
}

// ---------------------------------------------------------------------------
// Phase 2 (wave-decoupled async gather): out[e] = relu(U[src]+V[tar]).W2+b2.
// Block = 256 thr = 4 waves, 512 edges (128/wave, 16 batches of 8).
// Each WAVE owns a private 8 KB LDS region (2 buffers x 8 edges x 1 KB) and
// runs its own glds double-buffer pipeline with raw `s_waitcnt vmcnt(4)` —
// NO barriers in the loop, so waves never collectively drain vmcnt(0).
// Steady state: 8 glds (8 KB) in flight per wave; oldest batch is always
// ready after vmcnt(4) (stores issued between batches drain in order first).
// Batch layout (1 KB rows, glds dest = base + lane*16):
//   inst0: U rows edges 0-3   inst1: U rows edges 4-7
//   inst2: V rows edges 0-3   inst3: V rows edges 4-7
// ---------------------------------------------------------------------------
__global__ __launch_bounds__(256) void edge_score_async(
    const unsigned short* __restrict__ UVb,
    const int* __restrict__ pos,            // [2, E_POS]
    const int* __restrict__ neg,            // [2, E_NEG]
    const float* __restrict__ W2,           // [128]
    const float* __restrict__ b2,           // [1]
    float* __restrict__ out)                // [E_TOT]
{
    __shared__ unsigned short Ebuf[16384];  // 4 waves x 2 bufs x 2048 shorts
    __shared__ int sidx[512], tidx[512];

    const int t   = threadIdx.x;
    const int bid = blockIdx.x;
    const int e0  = bid * 512;                       // global edge base
    const int* eidx = (bid < 512) ? pos : neg;       // E_POS = 512*512
    const int lb    = (bid < 512) ? e0 : e0 - E_POS;

    {   // coalesced index staging (once; the only block barrier)
        const int2 sp = *(const int2*)(eidx + lb + 2 * t);
        const int2 tp = *(const int2*)(eidx + E_POS + lb + 2 * t);
        *(int2*)&sidx[2 * t] = sp;
        *(int2*)&tidx[2 * t] = tp;
    }
    __syncthreads();

    const int w     = t >> 6;
    const int lane  = t & 63;
    const int sub   = lane >> 4;            // 16-lane subgroup 0..3
    const int l16   = lane & 15;
    const int wbase = w * 128;              // wave's first local edge
    unsigned short* const wb0 = Ebuf + w * 4096;

    const float4 wa = *(const float4*)(W2 + l16 * 8);
    const float4 wv = *(const float4*)(W2 + l16 * 8 + 4);
    const float bb = b2[0];

#define ISSUE(b, lbuf)                                                       \
    do {                                                                     \
        const int eb_ = wbase + (b) * 8;                                     \
        const int n0_ = sidx[eb_ + sub];                                     \
        const int n1_ = sidx[eb_ + 4 + sub];                                 \
        const int n2_ = tidx[eb_ + sub];                                     \
        const int n3_ = tidx[eb_ + 4 + sub];                                 \
        glds16(UVb + (size_t)n0_ * 256       + l16 * 8, (lbuf));             \
        glds16(UVb + (size_t)n1_ * 256       + l16 * 8, (lbuf) + 512);       \
        glds16(UVb + (size_t)n2_ * 256 + 128 + l16 * 8, (lbuf) + 1024);     \
        glds16(UVb + (size_t)n3_ * 256 + 128 + l16 * 8, (lbuf) + 1536);     \
    } while (0)

#define BF_LO(uv) __uint_as_float((uv) << 16)
#define BF_HI(uv) __uint_as_float((uv) & 0xffff0000u)

    ISSUE(0, wb0);
#pragma unroll 1
    for (int b = 0; b < 16; ++b) {
        unsigned short* const cur = wb0 + (b & 1) * 2048;
        if (b < 15) {
            unsigned short* const nxt = wb0 + ((b + 1) & 1) * 2048;
            ISSUE(b + 1, nxt);
        }
        // wait for this batch's 4 glds (the oldest outstanding vm ops);
        // memory clobber pins LDS reads below / glds above this point.
        asm volatile("s_waitcnt vmcnt(4)" ::: "memory");

        const int ebg = e0 + wbase + b * 8;
#pragma unroll
        for (int i = 0; i < 2; ++i) {
            const int e = sub * 2 + i;      // 0..7
            const uint4 U = *(const uint4*)
                &cur[(e >> 2) * 512 + (e & 3) * 128 + l16 * 8];
            const uint4 V = *(const uint4*)
                &cur[1024 + (e >> 2) * 512 + (e & 3) * 128 + l16 * 8];
            float p = 0.f;
            p = fmaf(fmaxf(BF_LO(U.x) + BF_LO(V.x), 0.f), wa.x, p);
            p = fmaf(fmaxf(BF_HI(U.x) + BF_HI(V.x), 0.f), wa.y, p);
            p = fmaf(fmaxf(BF_LO(U.y) + BF_LO(V.y), 0.f), wa.z, p);
            p = fmaf(fmaxf(BF_HI(U.y) + BF_HI(V.y), 0.f), wa.w, p);
            p = fmaf(fmaxf(BF_LO(U.z) + BF_LO(V.z), 0.f), wv.x, p);
            p = fmaf(fmaxf(BF_HI(U.z) + BF_HI(V.z), 0.f), wv.y, p);
            p = fmaf(fmaxf(BF_LO(U.w) + BF_LO(V.w), 0.f), wv.z, p);
            p = fmaf(fmaxf(BF_HI(U.w) + BF_HI(V.w), 0.f), wv.w, p);
#pragma unroll
            for (int off = 8; off; off >>= 1) p += __shfl_xor(p, off, 64);
            if (l16 == 0) out[ebg + e] = p + bb;
        }
    }
#undef BF_LO
#undef BF_HI
#undef ISSUE
}

// ---------------------------------------------------------------------------
// Fallback (ws too small): one wave per edge, direct fp32 compute.
// ---------------------------------------------------------------------------
__global__ __launch_bounds__(64) void edge_naive(
    const float* __restrict__ x,
    const int* __restrict__ pos, const int* __restrict__ neg,
    const float* __restrict__ W1, const float* __restrict__ b1,
    const float* __restrict__ W2, const float* __restrict__ b2,
    float* __restrict__ out)
{
    const int lane = threadIdx.x;
    for (int e = blockIdx.x; e < E_TOT; e += gridDim.x) {
        int src, tar;
        if (e < E_POS) { src = pos[e]; tar = pos[E_POS + e]; }
        else { int e2 = e - E_POS; src = neg[e2]; tar = neg[E_NEG + e2]; }
        const float* xsrc = x + (size_t)src * D;
        const float* xtar = x + (size_t)tar * D;
        int j = lane * 2;
        float h0 = b1[j], h1 = b1[j + 1];
        for (int k = 0; k < D; ++k) {
            float a = xsrc[k], b = xtar[k];
            h0 = fmaf(a, W1[(size_t)k * D + j],       h0);
            h0 = fmaf(b, W1[(size_t)(k + D) * D + j], h0);
            h1 = fmaf(a, W1[(size_t)k * D + j + 1],       h1);
            h1 = fmaf(b, W1[(size_t)(k + D) * D + j + 1], h1);
        }
        float p = fmaf(fmaxf(h0, 0.f), W2[j], fmaxf(h1, 0.f) * W2[j + 1]);
#pragma unroll
        for (int off = 32; off > 0; off >>= 1) p += __shfl_xor(p, off, 64);
        if (lane == 0) out[e] = p + b2[0];
    }
}

extern "C" void kernel_launch(void* const* d_in, const int* in_sizes, int n_in,
                              void* d_out, int out_size, void* d_ws, size_t ws_size,
                              hipStream_t stream) {
    const float* x   = (const float*)d_in[0];
    const int*   pos = (const int*)d_in[1];
    const int*   neg = (const int*)d_in[2];
    const float* W1  = (const float*)d_in[3];
    const float* b1  = (const float*)d_in[4];
    const float* W2  = (const float*)d_in[5];
    const float* b2  = (const float*)d_in[6];
    float* out = (float*)d_out;

    const size_t uv_bytes = (size_t)N_NODES * 256 * sizeof(unsigned short);
    const size_t wf_bytes = 32768 * sizeof(unsigned short);
    if (ws_size >= uv_bytes + wf_bytes) {
        unsigned short* UVb = (unsigned short*)d_ws;
        unsigned short* Wfr = (unsigned short*)((char*)d_ws + uv_bytes);
        pack_w1<<<16, 256, 0, stream>>>(W1, Wfr);
        node_gemm_mfma<<<GRID1, 512, 0, stream>>>(x, Wfr, b1, UVb);
        edge_score_async<<<E_TOT / 512, 256, 0, stream>>>(UVb, pos, neg, W2, b2, out);
    } else {
        edge_naive<<<8192, 64, 0, stream>>>(x, pos, neg, W1, b1, W2, b2, out);
    }
}